// Round 1
// baseline (9495.234 us; speedup 1.0000x reference)
//
#include <hip/hip_runtime.h>
#include <math.h>

// ---------------------------------------------------------------------------
// Round 0: correct fp32 baseline. Direct convolutions, one thread per output
// element, blockIdx.y = cout so all weight indices are wave-uniform (scalar
// loads). Spatial index linear in x-fastest order -> coalesced input reads.
// ---------------------------------------------------------------------------

// k3 s1 SAME conv: in (Cin, S^3) -> out (cout slice of (Couts, S^3)).
// Optional residual add (addsrc, same shape as out), optional relu, output
// scale (used for the 0.5 VALUE_SCALER on feas).
__global__ __launch_bounds__(256) void conv_k3(
    const float* __restrict__ in, const float* __restrict__ w,
    const float* __restrict__ addsrc, float* __restrict__ out,
    int Cin, int S, int relu, float scale)
{
    const int S2 = S * S, S3 = S2 * S;
    int p = blockIdx.x * blockDim.x + threadIdx.x;
    if (p >= S3) return;
    const int x = p % S;
    const int y = (p / S) % S;
    const int z = p / S2;
    const int cout = blockIdx.y;
    const float* wc = w + (size_t)cout * Cin * 27;

    float acc = 0.f;
    for (int cin = 0; cin < Cin; ++cin) {
        const float* ic = in + (size_t)cin * S3;
        const float* wk = wc + cin * 27;
#pragma unroll
        for (int dz = 0; dz < 3; ++dz) {
            const int zz = z + dz - 1;
            if ((unsigned)zz >= (unsigned)S) continue;
#pragma unroll
            for (int dy = 0; dy < 3; ++dy) {
                const int yy = y + dy - 1;
                if ((unsigned)yy >= (unsigned)S) continue;
                const float* row = ic + zz * S2 + yy * S;
                const float* wr = wk + dz * 9 + dy * 3;
#pragma unroll
                for (int dx = 0; dx < 3; ++dx) {
                    const int xx = x + dx - 1;
                    if ((unsigned)xx >= (unsigned)S) continue;
                    acc = fmaf(row[xx], wr[dx], acc);
                }
            }
        }
    }
    if (addsrc) acc += addsrc[(size_t)cout * S3 + p];
    if (relu) acc = fmaxf(acc, 0.f);
    out[(size_t)cout * S3 + p] = acc * scale;
}

// k2 s2 VALID conv: in (Cin, (2*So)^3) -> out (cout slice of (Couts, So^3)).
__global__ __launch_bounds__(256) void conv_k2s2(
    const float* __restrict__ in, const float* __restrict__ w,
    float* __restrict__ out, int Cin, int So, int relu)
{
    const int So2 = So * So, So3 = So2 * So;
    int p = blockIdx.x * blockDim.x + threadIdx.x;
    if (p >= So3) return;
    const int Si = 2 * So;
    const int Si2 = Si * Si, Si3 = Si2 * Si;
    const int x = p % So;
    const int y = (p / So) % So;
    const int z = p / So2;
    const int cout = blockIdx.y;
    const float* wc = w + (size_t)cout * Cin * 8;
    const int base = 2 * z * Si2 + 2 * y * Si + 2 * x;

    float acc = 0.f;
    for (int cin = 0; cin < Cin; ++cin) {
        const float* ic = in + (size_t)cin * Si3 + base;
        const float* wk = wc + cin * 8;
        acc = fmaf(ic[0],          wk[0], acc);
        acc = fmaf(ic[1],          wk[1], acc);
        acc = fmaf(ic[Si],         wk[2], acc);
        acc = fmaf(ic[Si + 1],     wk[3], acc);
        acc = fmaf(ic[Si2],        wk[4], acc);
        acc = fmaf(ic[Si2 + 1],    wk[5], acc);
        acc = fmaf(ic[Si2 + Si],   wk[6], acc);
        acc = fmaf(ic[Si2 + Si + 1], wk[7], acc);
    }
    if (relu) acc = fmaxf(acc, 0.f);
    out[(size_t)cout * So3 + p] = acc;
}

// Fused gate: gates = relu(2 * conv_k2s2(hx_scaled, w_h)); cx *= sigmoid(gates).
// hx_scaled is the 0.5-scaled hx already written to d_out (32 ch @ Si=2*So);
// conv is linear so the stored 0.5 factor is undone by the *2.
__global__ __launch_bounds__(256) void gate_k2s2(
    const float* __restrict__ hx, const float* __restrict__ wh,
    float* __restrict__ cx, int So)
{
    const int So2 = So * So, So3 = So2 * So;
    int p = blockIdx.x * blockDim.x + threadIdx.x;
    if (p >= So3) return;
    const int Si = 2 * So;
    const int Si2 = Si * Si, Si3 = Si2 * Si;
    const int x = p % So;
    const int y = (p / So) % So;
    const int z = p / So2;
    const int cout = blockIdx.y;  // 0..63
    const float* wc = wh + (size_t)cout * 32 * 8;
    const int base = 2 * z * Si2 + 2 * y * Si + 2 * x;

    float acc = 0.f;
    for (int cin = 0; cin < 32; ++cin) {
        const float* ic = hx + (size_t)cin * Si3 + base;
        const float* wk = wc + cin * 8;
        acc = fmaf(ic[0],          wk[0], acc);
        acc = fmaf(ic[1],          wk[1], acc);
        acc = fmaf(ic[Si],         wk[2], acc);
        acc = fmaf(ic[Si + 1],     wk[3], acc);
        acc = fmaf(ic[Si2],        wk[4], acc);
        acc = fmaf(ic[Si2 + 1],    wk[5], acc);
        acc = fmaf(ic[Si2 + Si],   wk[6], acc);
        acc = fmaf(ic[Si2 + Si + 1], wk[7], acc);
    }
    acc *= 2.0f;                 // undo the 0.5 stored-hx scale
    acc = fmaxf(acc, 0.f);       // relu
    const float g = 1.0f / (1.0f + expf(-acc));  // sigmoid
    cx[(size_t)cout * So3 + p] *= g;
}

extern "C" void kernel_launch(void* const* d_in, const int* in_sizes, int n_in,
                              void* d_out, int out_size, void* d_ws, size_t ws_size,
                              hipStream_t stream)
{
    const float* x     = (const float*)d_in[0];
    const float* w_h   = (const float*)d_in[1];
    const float* w_c0  = (const float*)d_in[2];
    const float* w_r0  = (const float*)d_in[3];
    const float* w_r1  = (const float*)d_in[4];
    const float* w_c1  = (const float*)d_in[5];
    const float* w_out = (const float*)d_in[6];
    // d_in[7] = coder_num = 3 (setup constant; hard-coded)
    float* out = (float*)d_out;
    float* ws  = (float*)d_ws;

    // Workspace: 4 fp32 buffers of 64ch * 32^3 (8 MB each; sizes shrink later
    // iterations, we just reuse the max-size slots).
    const size_t BUF = (size_t)64 * 32 * 32 * 32;
    float* y_buf = ws;
    float* t_buf = ws + BUF;
    float* cx_a  = ws + 2 * BUF;
    float* cx_b  = ws + 3 * BUF;
    float* cx_bufs[2] = {cx_a, cx_b};

    // Output (feas) offsets: 32ch at 64^3, 32^3, 16^3, 8^3.
    size_t offs[4];
    offs[0] = 0;
    offs[1] = offs[0] + (size_t)32 * 64 * 64 * 64;
    offs[2] = offs[1] + (size_t)32 * 32 * 32 * 32;
    offs[3] = offs[2] + (size_t)32 * 16 * 16 * 16;

    const dim3 blk(256);

    // hx0 = 0.5 * conv_out(x)
    {
        const int S = 64;
        dim3 grid((S * S * S + 255) / 256, 32);
        conv_k3<<<grid, blk, 0, stream>>>(x, w_out, nullptr, out + offs[0], 64, S, 0, 0.5f);
    }

    const float* cx_cur = x;
    int S = 64;
    for (int i = 0; i < 3; ++i) {
        const int So = S / 2;
        float* cxn = cx_bufs[i & 1];
        dim3 grid64((So * So * So + 255) / 256, 64);
        dim3 grid32((So * So * So + 255) / 256, 32);

        // conv_c: ConvBlock(k2 s2, relu)
        conv_k2s2<<<grid64, blk, 0, stream>>>(cx_cur, w_c0, y_buf, 64, So, 1);
        // ResBlock: t = relu(conv_r0(y)); y = y + conv_r1(t)  (in-place add OK:
        // conv input is t_buf, addsrc read is the thread's own output index)
        conv_k3<<<grid64, blk, 0, stream>>>(y_buf, w_r0, nullptr, t_buf, 64, So, 1, 1.0f);
        conv_k3<<<grid64, blk, 0, stream>>>(t_buf, w_r1, y_buf, y_buf, 64, So, 0, 1.0f);
        // tail ConvBlock(k3 s1, act=None)
        conv_k3<<<grid64, blk, 0, stream>>>(y_buf, w_c1, nullptr, cxn, 64, So, 0, 1.0f);
        // gate: cx *= sigmoid(relu(conv_h(hx)))   (hx read 0.5-scaled from d_out)
        gate_k2s2<<<grid64, blk, 0, stream>>>(out + offs[i], w_h, cxn, So);
        // hx = conv_out(cx); store 0.5 * hx into d_out
        conv_k3<<<grid32, blk, 0, stream>>>(cxn, w_out, nullptr, out + offs[i + 1], 64, So, 0, 0.5f);

        cx_cur = cxn;
        S = So;
    }
}

// Round 2
// 4924.710 us; speedup vs baseline: 1.9281x; 1.9281x over previous
//
#include <hip/hip_runtime.h>
#include <math.h>

// ---------------------------------------------------------------------------
// Round 2: register-blocked direct conv. Each thread computes NC output
// channels for one spatial position: the 27-tap (or 8-tap) input neighborhood
// is loaded ONCE per cin and reused for NC FMAs each -> FMA:VMEM ratio NC:1
// (round-1 counters showed VALUBusy=13%: one load per FMA was the bound).
// Boundary handling is branchless: clamped row offsets (always in-bounds)
// + float masks folded into the loaded values.
// ---------------------------------------------------------------------------

template <int NC>
__global__ __launch_bounds__(256) void conv_k3(
    const float* __restrict__ in, const float* __restrict__ w,
    const float* __restrict__ addsrc, float* __restrict__ out,
    int Cin, int S, int relu, float scale)
{
    const int S2 = S * S, S3 = S2 * S;
    const int p = blockIdx.x * 256 + threadIdx.x;
    if (p >= S3) return;
    const int x = p % S;
    const int y = (p / S) % S;
    const int z = p / S2;
    const int cb = blockIdx.y * NC;

    // 9 clamped row offsets + row masks (computed once; reused for all cin).
    int   roff[9];
    float rmask[9];
#pragma unroll
    for (int dz = 0; dz < 3; ++dz) {
#pragma unroll
        for (int dy = 0; dy < 3; ++dy) {
            const int zz = z + dz - 1, yy = y + dy - 1;
            const bool v = ((unsigned)zz < (unsigned)S) && ((unsigned)yy < (unsigned)S);
            const int zc = min(max(zz, 0), S - 1);
            const int yc = min(max(yy, 0), S - 1);
            roff[dz * 3 + dy]  = zc * S2 + yc * S;
            rmask[dz * 3 + dy] = v ? 1.f : 0.f;
        }
    }
    const float mlo = (x > 0) ? 1.f : 0.f;
    const float mhi = (x < S - 1) ? 1.f : 0.f;
    const int xm1 = max(x - 1, 0);
    const int xp1 = min(x + 1, S - 1);

    float acc[NC];
#pragma unroll
    for (int c = 0; c < NC; ++c) acc[c] = 0.f;

    for (int cin = 0; cin < Cin; ++cin) {
        const float* ic = in + (size_t)cin * S3;
        float v[27];
#pragma unroll
        for (int r = 0; r < 9; ++r) {
            const float m = rmask[r];
            const float* row = ic + roff[r];
            v[r * 3 + 0] = row[xm1] * (m * mlo);
            v[r * 3 + 1] = row[x]   * m;
            v[r * 3 + 2] = row[xp1] * (m * mhi);
        }
#pragma unroll
        for (int c = 0; c < NC; ++c) {
            const float* wk = w + (((size_t)(cb + c)) * Cin + cin) * 27;  // wave-uniform -> scalar loads
#pragma unroll
            for (int k = 0; k < 27; ++k) acc[c] = fmaf(v[k], wk[k], acc[c]);
        }
    }

#pragma unroll
    for (int c = 0; c < NC; ++c) {
        float a = acc[c];
        if (addsrc) a += addsrc[(size_t)(cb + c) * S3 + p];
        if (relu) a = fmaxf(a, 0.f);
        out[(size_t)(cb + c) * S3 + p] = a * scale;
    }
}

// k2 s2 VALID conv (no padding -> no masks needed at all).
template <int NC>
__global__ __launch_bounds__(256) void conv_k2s2(
    const float* __restrict__ in, const float* __restrict__ w,
    float* __restrict__ out, int Cin, int So, int relu)
{
    const int So2 = So * So, So3 = So2 * So;
    const int p = blockIdx.x * 256 + threadIdx.x;
    if (p >= So3) return;
    const int Si = 2 * So, Si2 = Si * Si, Si3 = Si2 * Si;
    const int x = p % So;
    const int y = (p / So) % So;
    const int z = p / So2;
    const int cb = blockIdx.y * NC;
    const int base = 2 * z * Si2 + 2 * y * Si + 2 * x;

    float acc[NC];
#pragma unroll
    for (int c = 0; c < NC; ++c) acc[c] = 0.f;

    for (int cin = 0; cin < Cin; ++cin) {
        const float* ic = in + (size_t)cin * Si3 + base;
        float v[8];
        v[0] = ic[0];          v[1] = ic[1];
        v[2] = ic[Si];         v[3] = ic[Si + 1];
        v[4] = ic[Si2];        v[5] = ic[Si2 + 1];
        v[6] = ic[Si2 + Si];   v[7] = ic[Si2 + Si + 1];
#pragma unroll
        for (int c = 0; c < NC; ++c) {
            const float* wk = w + (((size_t)(cb + c)) * Cin + cin) * 8;
#pragma unroll
            for (int k = 0; k < 8; ++k) acc[c] = fmaf(v[k], wk[k], acc[c]);
        }
    }
#pragma unroll
    for (int c = 0; c < NC; ++c) {
        float a = acc[c];
        if (relu) a = fmaxf(a, 0.f);
        out[(size_t)(cb + c) * So3 + p] = a;
    }
}

// Fused gate: cx *= sigmoid(relu(2 * conv_k2s2(hx_scaled, w_h))).
// hx_scaled is the 0.5-scaled hx already in d_out; the conv is linear so the
// stored 0.5 is undone by the *2.
template <int NC>
__global__ __launch_bounds__(256) void gate_k2s2(
    const float* __restrict__ hx, const float* __restrict__ wh,
    float* __restrict__ cx, int So)
{
    const int So2 = So * So, So3 = So2 * So;
    const int p = blockIdx.x * 256 + threadIdx.x;
    if (p >= So3) return;
    const int Si = 2 * So, Si2 = Si * Si, Si3 = Si2 * Si;
    const int x = p % So;
    const int y = (p / So) % So;
    const int z = p / So2;
    const int cb = blockIdx.y * NC;
    const int base = 2 * z * Si2 + 2 * y * Si + 2 * x;

    float acc[NC];
#pragma unroll
    for (int c = 0; c < NC; ++c) acc[c] = 0.f;

    for (int cin = 0; cin < 32; ++cin) {
        const float* ic = hx + (size_t)cin * Si3 + base;
        float v[8];
        v[0] = ic[0];          v[1] = ic[1];
        v[2] = ic[Si];         v[3] = ic[Si + 1];
        v[4] = ic[Si2];        v[5] = ic[Si2 + 1];
        v[6] = ic[Si2 + Si];   v[7] = ic[Si2 + Si + 1];
#pragma unroll
        for (int c = 0; c < NC; ++c) {
            const float* wk = wh + (((size_t)(cb + c)) * 32 + cin) * 8;
#pragma unroll
            for (int k = 0; k < 8; ++k) acc[c] = fmaf(v[k], wk[k], acc[c]);
        }
    }
#pragma unroll
    for (int c = 0; c < NC; ++c) {
        float a = fmaxf(acc[c] * 2.0f, 0.f);
        const float g = 1.0f / (1.0f + __expf(-a));
        cx[(size_t)(cb + c) * So3 + p] *= g;
    }
}

extern "C" void kernel_launch(void* const* d_in, const int* in_sizes, int n_in,
                              void* d_out, int out_size, void* d_ws, size_t ws_size,
                              hipStream_t stream)
{
    const float* x     = (const float*)d_in[0];
    const float* w_h   = (const float*)d_in[1];
    const float* w_c0  = (const float*)d_in[2];
    const float* w_r0  = (const float*)d_in[3];
    const float* w_r1  = (const float*)d_in[4];
    const float* w_c1  = (const float*)d_in[5];
    const float* w_out = (const float*)d_in[6];
    float* out = (float*)d_out;
    float* ws  = (float*)d_ws;

    const size_t BUF = (size_t)64 * 32 * 32 * 32;  // 64ch @ 32^3 fp32
    float* y_buf = ws;
    float* t_buf = ws + BUF;
    float* cx_a  = ws + 2 * BUF;
    float* cx_b  = ws + 3 * BUF;
    float* cx_bufs[2] = {cx_a, cx_b};

    size_t offs[4];
    offs[0] = 0;
    offs[1] = offs[0] + (size_t)32 * 64 * 64 * 64;
    offs[2] = offs[1] + (size_t)32 * 32 * 32 * 32;
    offs[3] = offs[2] + (size_t)32 * 16 * 16 * 16;

    const dim3 blk(256);

    // hx0 = 0.5 * conv_out(x): 64^3, Cout=32, NC=32 -> grid (1024,1)
    {
        const int S = 64;
        dim3 grid(S * S * S / 256, 32 / 32);
        conv_k3<32><<<grid, blk, 0, stream>>>(x, w_out, nullptr, out + offs[0], 64, S, 0, 0.5f);
    }

    const float* cx_cur = x;
    int S = 64;
    for (int i = 0; i < 3; ++i) {
        const int So = S / 2;
        float* cxn = cx_bufs[i & 1];
        const int sb = So * So * So / 256;        // spatial blocks (So>=8 -> So^3 % 256 == 0)

        if (So >= 32) {
            dim3 g64(sb, 64 / 16), g32(sb, 32 / 16);
            conv_k2s2<16><<<g64, blk, 0, stream>>>(cx_cur, w_c0, y_buf, 64, So, 1);
            conv_k3<16><<<g64, blk, 0, stream>>>(y_buf, w_r0, nullptr, t_buf, 64, So, 1, 1.0f);
            conv_k3<16><<<g64, blk, 0, stream>>>(t_buf, w_r1, y_buf, y_buf, 64, So, 0, 1.0f);
            conv_k3<16><<<g64, blk, 0, stream>>>(y_buf, w_c1, nullptr, cxn, 64, So, 0, 1.0f);
            gate_k2s2<16><<<g64, blk, 0, stream>>>(out + offs[i], w_h, cxn, So);
            conv_k3<16><<<g32, blk, 0, stream>>>(cxn, w_out, nullptr, out + offs[i + 1], 64, So, 0, 0.5f);
        } else {
            // deep levels: few spatial blocks -> smaller NC for more grid parallelism
            const int sb2 = (So * So * So + 255) / 256;
            dim3 g64(sb2, 64 / 8), g32(sb2, 32 / 8);
            conv_k2s2<8><<<g64, blk, 0, stream>>>(cx_cur, w_c0, y_buf, 64, So, 1);
            conv_k3<8><<<g64, blk, 0, stream>>>(y_buf, w_r0, nullptr, t_buf, 64, So, 1, 1.0f);
            conv_k3<8><<<g64, blk, 0, stream>>>(t_buf, w_r1, y_buf, y_buf, 64, So, 0, 1.0f);
            conv_k3<8><<<g64, blk, 0, stream>>>(y_buf, w_c1, nullptr, cxn, 64, So, 0, 1.0f);
            gate_k2s2<8><<<g64, blk, 0, stream>>>(out + offs[i], w_h, cxn, So);
            conv_k3<8><<<g32, blk, 0, stream>>>(cxn, w_out, nullptr, out + offs[i + 1], 64, So, 0, 0.5f);
        }

        cx_cur = cxn;
        S = So;
    }
}

// Round 3
// 792.349 us; speedup vs baseline: 11.9837x; 6.2153x over previous
//
#include <hip/hip_runtime.h>
#include <math.h>

// ---------------------------------------------------------------------------
// Round 3: f16 MFMA implicit-GEMM conv with hi/lo split-precision emulation.
// Need ~1.15e-4 relative accuracy (ref absmax 454, threshold 5.2e-2) -> raw
// f16 (2^-11) insufficient. Classic 3-pass emulation: acc += wh*bh + wh*bl +
// wl*bh with w = wh+wl, a = ah+al (each f16 pair). Products exact to ~2^-22.
// A = weights packed in exact MFMA lane order (prep kernel); B = activations
// staged to LDS as [32 hi | 32 lo] per pixel, stride 88 f16 (16B aligned,
// 2-way-max bank pattern = free). Activations in ws: f16 hi/lo position-major
// [p][128]. x / d_out inputs staged from f32 channel-major directly.
// ---------------------------------------------------------------------------

typedef _Float16 f16;
typedef _Float16 f16x8 __attribute__((ext_vector_type(8)));
typedef _Float16 f16x4 __attribute__((ext_vector_type(4)));
typedef float    f32x4 __attribute__((ext_vector_type(4)));

#define PIX 88   // f16 per LDS pixel: 64 payload (32 hi | 32 lo) + 24 pad

// Pack weights into MFMA A-fragment order.
// entry e = ((tap*CH + h)*2 + sel)*NMT + gmt ; lane l: cout = gmt*16 + (l&15),
// cin = h*32 + ((l>>4)&3)*8 + j. sel 0 = hi, 1 = lo residual.
__global__ void pack_w(const float* __restrict__ w, f16* __restrict__ wp,
                       int Cin, int taps, int CH, int NMT)
{
    const int lane = threadIdx.x;  // 0..63
    const int e   = blockIdx.x;
    const int gmt = e % NMT;
    const int sel = (e / NMT) % 2;
    const int h   = (e / (NMT * 2)) % CH;
    const int tap = e / (NMT * 2 * CH);
    const int cout = gmt * 16 + (lane & 15);
    const int cin0 = h * 32 + ((lane >> 4) & 3) * 8;
    f16x8 v;
    for (int j = 0; j < 8; ++j) {
        float x = w[((size_t)cout * Cin + cin0 + j) * taps + tap];
        f16 hi = (f16)x;
        v[j] = sel ? (f16)(x - (float)hi) : hi;
    }
    *(f16x8*)&wp[((size_t)e * 64 + lane) * 8] = v;
}

// ---------------- k3 s1 SAME conv, Cin=64 ----------------
// Workgroup = 32 output positions (1 row x 32 for S>=32, else 32/S rows) x all
// couts. Wave w: n-tile = w&1 (16 pos), m-half = w>>1.
template<int S, int NMT, int MTW, bool SRCF32>
__global__ __launch_bounds__(256) void conv_k3(
    const void* __restrict__ in_, const f16* __restrict__ wp,
    const f16* __restrict__ addsrc, f16* __restrict__ act_out,
    float* __restrict__ f32_out, int relu, float scale)
{
    constexpr int S2 = S * S, S3 = S2 * S;
    constexpr int TXW = (S >= 32) ? 32 : S;
    constexpr int NY  = 32 / TXW;
    constexpr int NXC = S / ((S >= 32) ? 32 : S);   // 2 when S==64, else 1
    constexpr int XP  = TXW + 2;
    constexpr int RY  = NY + 2;
    constexpr int NROW = 3 * RY;
    constexpr int CH = 2;
    __shared__ __align__(16) f16 sm[NROW * XP * PIX];

    const int bid = blockIdx.x;
    const int xc = bid % NXC;
    const int yb = (bid / NXC) % (S / NY);
    const int zb = bid / (NXC * (S / NY));
    const int y0 = yb * NY;
    const int x0 = xc * TXW;

    const int tid  = threadIdx.x;
    const int lane = tid & 63;
    const int wave = tid >> 6;
    const int l15  = lane & 15, quad = (lane >> 4) & 3;
    const int nt = wave & 1, mh = wave >> 1;
    const int pl = nt * 16 + l15;
    const int yl = pl / TXW, xl = pl % TXW;

    f32x4 acc[MTW];
#pragma unroll
    for (int m = 0; m < MTW; ++m) { f32x4 z = {0.f, 0.f, 0.f, 0.f}; acc[m] = z; }

    for (int h = 0; h < CH; ++h) {
        __syncthreads();
        constexpr int NIT = NROW * XP * 8;
        if (SRCF32) {
            const float* src = (const float*)in_;
            for (int it = tid; it < NIT; it += 256) {
                const int xp = it % XP;
                const int rr = (it / XP) % NROW;
                const int cc = it / (XP * NROW);
                const int zr = rr / RY, yr = rr % RY;
                const int pz = zb + zr - 1, py = y0 + yr - 1, px = x0 + xp - 1;
                const bool ok = (unsigned)pz < (unsigned)S && (unsigned)py < (unsigned)S
                             && (unsigned)px < (unsigned)S;
                const int cbase = h * 32 + (cc & 3) * 8;
                f16x8 v;
                if (ok) {
                    const size_t p = (size_t)(pz * S2 + py * S + px);
#pragma unroll
                    for (int j = 0; j < 8; ++j) {
                        float x = src[(size_t)(cbase + j) * S3 + p];
                        f16 hi = (f16)x;
                        v[j] = (cc < 4) ? hi : (f16)(x - (float)hi);
                    }
                } else {
#pragma unroll
                    for (int j = 0; j < 8; ++j) v[j] = (f16)0.f;
                }
                *(f16x8*)&sm[(rr * XP + xp) * PIX + (cc < 4 ? cc * 8 : 32 + (cc - 4) * 8)] = v;
            }
        } else {
            const f16* src = (const f16*)in_;
            for (int it = tid; it < NIT; it += 256) {
                const int cc = it % 8;
                const int xp = (it / 8) % XP;
                const int rr = it / (8 * XP);
                const int zr = rr / RY, yr = rr % RY;
                const int pz = zb + zr - 1, py = y0 + yr - 1, px = x0 + xp - 1;
                const bool ok = (unsigned)pz < (unsigned)S && (unsigned)py < (unsigned)S
                             && (unsigned)px < (unsigned)S;
                f16x8 v;
                if (ok) {
                    const size_t p = (size_t)(pz * S2 + py * S + px);
                    const int off = (cc < 4) ? (h * 32 + cc * 8) : (64 + h * 32 + (cc - 4) * 8);
                    v = *(const f16x8*)&src[p * 128 + off];
                } else {
#pragma unroll
                    for (int j = 0; j < 8; ++j) v[j] = (f16)0.f;
                }
                *(f16x8*)&sm[(rr * XP + xp) * PIX + (cc < 4 ? cc * 8 : 32 + (cc - 4) * 8)] = v;
            }
        }
        __syncthreads();

        for (int dz = 0; dz < 3; ++dz) {
#pragma unroll
            for (int dy = 0; dy < 3; ++dy) {
#pragma unroll
                for (int dx = 0; dx < 3; ++dx) {
                    const int tap = dz * 9 + dy * 3 + dx;
                    const int pix = ((dz * RY) + yl + dy) * XP + (xl + dx);
                    const f16x8 bh = *(const f16x8*)&sm[pix * PIX + quad * 8];
                    const f16x8 bl = *(const f16x8*)&sm[pix * PIX + 32 + quad * 8];
#pragma unroll
                    for (int m = 0; m < MTW; ++m) {
                        const int gmt = mh * MTW + m;
                        const size_t eh = ((size_t)((tap * CH + h) * 2 + 0) * NMT + gmt) * 512 + lane * 8;
                        const size_t el = ((size_t)((tap * CH + h) * 2 + 1) * NMT + gmt) * 512 + lane * 8;
                        const f16x8 awh = *(const f16x8*)&wp[eh];
                        const f16x8 awl = *(const f16x8*)&wp[el];
                        acc[m] = __builtin_amdgcn_mfma_f32_16x16x32_f16(awh, bh, acc[m], 0, 0, 0);
                        acc[m] = __builtin_amdgcn_mfma_f32_16x16x32_f16(awh, bl, acc[m], 0, 0, 0);
                        acc[m] = __builtin_amdgcn_mfma_f32_16x16x32_f16(awl, bh, acc[m], 0, 0, 0);
                    }
                }
            }
        }
    }

    // epilogue: C/D layout col(=pos)=lane&15, row(=cout_local)=quad*4+r
    const int pg = (zb * S + y0 + yl) * S + x0 + xl;
#pragma unroll
    for (int m = 0; m < MTW; ++m) {
        const int gmt = mh * MTW + m;
        float a[4];
#pragma unroll
        for (int r = 0; r < 4; ++r) a[r] = acc[m][r];
        if (addsrc) {
            const f16x4 ah = *(const f16x4*)&addsrc[(size_t)pg * 128 + gmt * 16 + quad * 4];
            const f16x4 al = *(const f16x4*)&addsrc[(size_t)pg * 128 + 64 + gmt * 16 + quad * 4];
#pragma unroll
            for (int r = 0; r < 4; ++r) a[r] += (float)ah[r] + (float)al[r];
        }
        if (relu) {
#pragma unroll
            for (int r = 0; r < 4; ++r) a[r] = fmaxf(a[r], 0.f);
        }
        if (act_out) {
            f16x4 hi, lo;
#pragma unroll
            for (int r = 0; r < 4; ++r) {
                hi[r] = (f16)a[r];
                lo[r] = (f16)(a[r] - (float)hi[r]);
            }
            *(f16x4*)&act_out[(size_t)pg * 128 + gmt * 16 + quad * 4] = hi;
            *(f16x4*)&act_out[(size_t)pg * 128 + 64 + gmt * 16 + quad * 4] = lo;
        }
        if (f32_out) {
#pragma unroll
            for (int r = 0; r < 4; ++r)
                f32_out[(size_t)(gmt * 16 + quad * 4 + r) * S3 + pg] = a[r] * scale;
        }
    }
}

// ---------------- k2 s2 VALID conv ----------------
// GATE=false: conv_c0 (Cin=64, relu, act out). GATE=true: Cin=32, RMW
// cx *= sigmoid(relu(acc)); input f32 (0.5-scaled hx) with src_scale=2.
template<int So, int NMT, int MTW, bool SRCF32, bool GATE>
__global__ __launch_bounds__(256) void conv_k2(
    const void* __restrict__ in_, const f16* __restrict__ wp,
    f16* __restrict__ act_out, f16* __restrict__ cx, float src_scale)
{
    constexpr int So2 = So * So, So3 = So2 * So;
    constexpr int Si = 2 * So, Si2 = Si * Si, Si3 = Si2 * Si;
    constexpr int OW  = (So >= 32) ? 32 : So;
    constexpr int NYo = 32 / OW;
    constexpr int RYI = 2 * NYo;
    constexpr int NROW = 2 * RYI;
    constexpr int CH = GATE ? 1 : 2;
    __shared__ __align__(16) f16 sm[NROW * Si * PIX];

    const int yb = blockIdx.x % (So / NYo);
    const int zb = blockIdx.x / (So / NYo);
    const int y0 = yb * NYo;

    const int tid  = threadIdx.x;
    const int lane = tid & 63;
    const int wave = tid >> 6;
    const int l15  = lane & 15, quad = (lane >> 4) & 3;
    const int nt = wave & 1, mh = wave >> 1;
    const int pl = nt * 16 + l15;
    const int yl = pl / OW, xl = pl % OW;

    f32x4 acc[MTW];
#pragma unroll
    for (int m = 0; m < MTW; ++m) { f32x4 z = {0.f, 0.f, 0.f, 0.f}; acc[m] = z; }

    for (int h = 0; h < CH; ++h) {
        __syncthreads();
        constexpr int NIT = NROW * Si * 8;
        if (SRCF32) {
            const float* src = (const float*)in_;
            for (int it = tid; it < NIT; it += 256) {
                const int xp = it % Si;
                const int rr = (it / Si) % NROW;
                const int cc = it / (Si * NROW);
                const int zr = rr / RYI, yr = rr % RYI;
                const size_t p = (size_t)((2 * zb + zr) * Si2 + (2 * y0 + yr) * Si + xp);
                const int cbase = h * 32 + (cc & 3) * 8;
                f16x8 v;
#pragma unroll
                for (int j = 0; j < 8; ++j) {
                    float x = src[(size_t)(cbase + j) * Si3 + p] * src_scale;
                    f16 hi = (f16)x;
                    v[j] = (cc < 4) ? hi : (f16)(x - (float)hi);
                }
                *(f16x8*)&sm[(rr * Si + xp) * PIX + (cc < 4 ? cc * 8 : 32 + (cc - 4) * 8)] = v;
            }
        } else {
            const f16* src = (const f16*)in_;
            for (int it = tid; it < NIT; it += 256) {
                const int cc = it % 8;
                const int xp = (it / 8) % Si;
                const int rr = it / (8 * Si);
                const int zr = rr / RYI, yr = rr % RYI;
                const size_t p = (size_t)((2 * zb + zr) * Si2 + (2 * y0 + yr) * Si + xp);
                const int off = (cc < 4) ? (h * 32 + cc * 8) : (64 + h * 32 + (cc - 4) * 8);
                f16x8 v = *(const f16x8*)&src[p * 128 + off];
                *(f16x8*)&sm[(rr * Si + xp) * PIX + (cc < 4 ? cc * 8 : 32 + (cc - 4) * 8)] = v;
            }
        }
        __syncthreads();

#pragma unroll
        for (int dz = 0; dz < 2; ++dz) {
#pragma unroll
            for (int dy = 0; dy < 2; ++dy) {
#pragma unroll
                for (int dx = 0; dx < 2; ++dx) {
                    const int tap = dz * 4 + dy * 2 + dx;
                    const int pix = (dz * RYI + 2 * yl + dy) * Si + 2 * xl + dx;
                    const f16x8 bh = *(const f16x8*)&sm[pix * PIX + quad * 8];
                    const f16x8 bl = *(const f16x8*)&sm[pix * PIX + 32 + quad * 8];
#pragma unroll
                    for (int m = 0; m < MTW; ++m) {
                        const int gmt = mh * MTW + m;
                        const size_t eh = ((size_t)((tap * CH + h) * 2 + 0) * NMT + gmt) * 512 + lane * 8;
                        const size_t el = ((size_t)((tap * CH + h) * 2 + 1) * NMT + gmt) * 512 + lane * 8;
                        const f16x8 awh = *(const f16x8*)&wp[eh];
                        const f16x8 awl = *(const f16x8*)&wp[el];
                        acc[m] = __builtin_amdgcn_mfma_f32_16x16x32_f16(awh, bh, acc[m], 0, 0, 0);
                        acc[m] = __builtin_amdgcn_mfma_f32_16x16x32_f16(awh, bl, acc[m], 0, 0, 0);
                        acc[m] = __builtin_amdgcn_mfma_f32_16x16x32_f16(awl, bh, acc[m], 0, 0, 0);
                    }
                }
            }
        }
    }

    const int pg = (zb * So + y0 + yl) * So + xl;
#pragma unroll
    for (int m = 0; m < MTW; ++m) {
        const int gmt = mh * MTW + m;
        if (GATE) {
            f16x4 chi = *(const f16x4*)&cx[(size_t)pg * 128 + gmt * 16 + quad * 4];
            f16x4 clo = *(const f16x4*)&cx[(size_t)pg * 128 + 64 + gmt * 16 + quad * 4];
            f16x4 nhi, nlo;
#pragma unroll
            for (int r = 0; r < 4; ++r) {
                const float g = 1.0f / (1.0f + expf(-fmaxf(acc[m][r], 0.f)));
                float v = ((float)chi[r] + (float)clo[r]) * g;
                f16 hi = (f16)v;
                nhi[r] = hi;
                nlo[r] = (f16)(v - (float)hi);
            }
            *(f16x4*)&cx[(size_t)pg * 128 + gmt * 16 + quad * 4] = nhi;
            *(f16x4*)&cx[(size_t)pg * 128 + 64 + gmt * 16 + quad * 4] = nlo;
        } else {
            f16x4 hi, lo;
#pragma unroll
            for (int r = 0; r < 4; ++r) {
                const float a = fmaxf(acc[m][r], 0.f);   // ConvBlock relu
                hi[r] = (f16)a;
                lo[r] = (f16)(a - (float)hi[r]);
            }
            *(f16x4*)&act_out[(size_t)pg * 128 + gmt * 16 + quad * 4] = hi;
            *(f16x4*)&act_out[(size_t)pg * 128 + 64 + gmt * 16 + quad * 4] = lo;
        }
    }
}

extern "C" void kernel_launch(void* const* d_in, const int* in_sizes, int n_in,
                              void* d_out, int out_size, void* d_ws, size_t ws_size,
                              hipStream_t stream)
{
    const float* x     = (const float*)d_in[0];
    const float* w_h   = (const float*)d_in[1];
    const float* w_c0  = (const float*)d_in[2];
    const float* w_r0  = (const float*)d_in[3];
    const float* w_r1  = (const float*)d_in[4];
    const float* w_c1  = (const float*)d_in[5];
    const float* w_out = (const float*)d_in[6];
    float* out = (float*)d_out;
    f16* ws = (f16*)d_ws;

    // ws layout (f16 units)
    size_t o = 0;
    f16* wp_h   = ws + o; o += (size_t)8 * 1 * 2 * 4 * 512;    //  32768
    f16* wp_c0  = ws + o; o += (size_t)8 * 2 * 2 * 4 * 512;    //  65536
    f16* wp_r0  = ws + o; o += (size_t)27 * 2 * 2 * 4 * 512;   // 221184
    f16* wp_r1  = ws + o; o += (size_t)27 * 2 * 2 * 4 * 512;
    f16* wp_c1  = ws + o; o += (size_t)27 * 2 * 2 * 4 * 512;
    f16* wp_out = ws + o; o += (size_t)27 * 2 * 2 * 2 * 512;   // 110592
    const size_t ABUF = (size_t)32 * 32 * 32 * 128;            // 4.19M f16
    f16* y_buf = ws + o; o += ABUF;
    f16* t_buf = ws + o; o += ABUF;
    f16* cx    = ws + o; o += ABUF;

    size_t offs[4];
    offs[0] = 0;
    offs[1] = offs[0] + (size_t)32 * 64 * 64 * 64;
    offs[2] = offs[1] + (size_t)32 * 32 * 32 * 32;
    offs[3] = offs[2] + (size_t)32 * 16 * 16 * 16;

    const dim3 blk(256);

    // weight packing (every call: ws is re-poisoned by harness)
    pack_w<<<dim3(8  * 1 * 2 * 4), dim3(64), 0, stream>>>(w_h,   wp_h,   32, 8,  1, 4);
    pack_w<<<dim3(8  * 2 * 2 * 4), dim3(64), 0, stream>>>(w_c0,  wp_c0,  64, 8,  2, 4);
    pack_w<<<dim3(27 * 2 * 2 * 4), dim3(64), 0, stream>>>(w_r0,  wp_r0,  64, 27, 2, 4);
    pack_w<<<dim3(27 * 2 * 2 * 4), dim3(64), 0, stream>>>(w_r1,  wp_r1,  64, 27, 2, 4);
    pack_w<<<dim3(27 * 2 * 2 * 4), dim3(64), 0, stream>>>(w_c1,  wp_c1,  64, 27, 2, 4);
    pack_w<<<dim3(27 * 2 * 2 * 2), dim3(64), 0, stream>>>(w_out, wp_out, 64, 27, 2, 2);

    // hx0 = 0.5 * conv_out(x)    (S=64, grid = NXC*(S/NY)*S = 2*64*64)
    conv_k3<64, 2, 1, true><<<dim3(8192), blk, 0, stream>>>(
        x, wp_out, nullptr, nullptr, out + offs[0], 0, 0.5f);

    // ---- level 0: 64 -> 32 ----
    conv_k2<32, 4, 2, true,  false><<<dim3(1024), blk, 0, stream>>>(x, wp_c0, y_buf, nullptr, 1.f);
    conv_k3<32, 4, 2, false><<<dim3(1024), blk, 0, stream>>>(y_buf, wp_r0, nullptr, t_buf, nullptr, 1, 1.f);
    conv_k3<32, 4, 2, false><<<dim3(1024), blk, 0, stream>>>(t_buf, wp_r1, y_buf, y_buf, nullptr, 0, 1.f);
    conv_k3<32, 4, 2, false><<<dim3(1024), blk, 0, stream>>>(y_buf, wp_c1, nullptr, cx, nullptr, 0, 1.f);
    conv_k2<32, 4, 2, true,  true ><<<dim3(1024), blk, 0, stream>>>(out + offs[0], wp_h, nullptr, cx, 2.f);
    conv_k3<32, 2, 1, false><<<dim3(1024), blk, 0, stream>>>(cx, wp_out, nullptr, nullptr, out + offs[1], 0, 0.5f);

    // ---- level 1: 32 -> 16 ----
    conv_k2<16, 4, 2, false, false><<<dim3(128), blk, 0, stream>>>(cx, wp_c0, y_buf, nullptr, 1.f);
    conv_k3<16, 4, 2, false><<<dim3(128), blk, 0, stream>>>(y_buf, wp_r0, nullptr, t_buf, nullptr, 1, 1.f);
    conv_k3<16, 4, 2, false><<<dim3(128), blk, 0, stream>>>(t_buf, wp_r1, y_buf, y_buf, nullptr, 0, 1.f);
    conv_k3<16, 4, 2, false><<<dim3(128), blk, 0, stream>>>(y_buf, wp_c1, nullptr, cx, nullptr, 0, 1.f);
    conv_k2<16, 4, 2, true,  true ><<<dim3(128), blk, 0, stream>>>(out + offs[1], wp_h, nullptr, cx, 2.f);
    conv_k3<16, 2, 1, false><<<dim3(128), blk, 0, stream>>>(cx, wp_out, nullptr, nullptr, out + offs[2], 0, 0.5f);

    // ---- level 2: 16 -> 8 ----
    conv_k2<8, 4, 2, false, false><<<dim3(16), blk, 0, stream>>>(cx, wp_c0, y_buf, nullptr, 1.f);
    conv_k3<8, 4, 2, false><<<dim3(16), blk, 0, stream>>>(y_buf, wp_r0, nullptr, t_buf, nullptr, 1, 1.f);
    conv_k3<8, 4, 2, false><<<dim3(16), blk, 0, stream>>>(t_buf, wp_r1, y_buf, y_buf, nullptr, 0, 1.f);
    conv_k3<8, 4, 2, false><<<dim3(16), blk, 0, stream>>>(y_buf, wp_c1, nullptr, cx, nullptr, 0, 1.f);
    conv_k2<8, 4, 2, true,  true ><<<dim3(16), blk, 0, stream>>>(out + offs[2], wp_h, nullptr, cx, 2.f);
    conv_k3<8, 2, 1, false><<<dim3(16), blk, 0, stream>>>(cx, wp_out, nullptr, nullptr, out + offs[3], 0, 0.5f);
}